// Round 1
// baseline (227.958 us; speedup 1.0000x reference)
//
#include <hip/hip_runtime.h>
#include <hip/hip_bf16.h>

typedef _Float16 f16;
typedef _Float16 f16x8 __attribute__((ext_vector_type(8)));
typedef float f32x4 __attribute__((ext_vector_type(4)));

#define NB 32
#define NM 64
#define NC 36
#define NEG_INF_F (-1e10f)

// ---------------- conversion kernels ----------------

__global__ __launch_bounds__(256) void cvt_dense(const float* __restrict__ in,
                                                 f16* __restrict__ out, int n) {
    int i = blockIdx.x * 256 + threadIdx.x;
    if (i < n) out[i] = (f16)in[i];
}

// out: rows x 1024 (zero-padded), in: rows x K
__global__ __launch_bounds__(256) void cvt_pad1024(const float* __restrict__ in,
                                                   f16* __restrict__ out, int rows, int K) {
    int i = blockIdx.x * 256 + threadIdx.x;
    int r = i >> 10, k = i & 1023;
    if (r < rows) out[i] = (k < K) ? (f16)in[r * K + k] : (f16)0.f;
}

// w: K x 512 (row-major f32) -> wt: 512 x Kp (f16, k-major, zero-padded)
// thread i: n = i & 511 (coalesced read), k = i >> 9
__global__ __launch_bounds__(256) void cvt_transpose(const float* __restrict__ w,
                                                     f16* __restrict__ wt, int K, int Kp) {
    int i = blockIdx.x * 256 + threadIdx.x;
    int n = i & 511;
    int k = i >> 9;
    if (k < Kp) wt[n * Kp + k] = (k < K) ? (f16)w[k * 512 + n] : (f16)0.f;
}

// ---------------- generic f16 MFMA GEMM: out = act(A @ Wt^T + bias) ----------------
// A: R x K (f16 row-major, stride K), Wt: N x K (f16, k-contiguous), out: R x N f16
__global__ __launch_bounds__(256) void gemm16(const f16* __restrict__ A,
                                              const f16* __restrict__ Wt,
                                              const float* __restrict__ bias,
                                              f16* __restrict__ out,
                                              int K, int N, int relu) {
    int lane = threadIdx.x & 63;
    int w = threadIdx.x >> 6;
    int wr = w >> 1, wc = w & 1;
    int m0 = blockIdx.x * 64 + wr * 32;
    int n0 = blockIdx.y * 64 + wc * 32;
    int rl = lane & 15, kg = lane >> 4;

    f32x4 acc[2][2] = {};

    const f16* a0p = A + (m0 + rl) * K + kg * 8;
    const f16* a1p = a0p + 16 * K;
    const f16* b0p = Wt + (n0 + rl) * K + kg * 8;
    const f16* b1p = b0p + 16 * K;

    for (int k0 = 0; k0 < K; k0 += 32) {
        f16x8 a0 = *(const f16x8*)(a0p + k0);
        f16x8 a1 = *(const f16x8*)(a1p + k0);
        f16x8 b0 = *(const f16x8*)(b0p + k0);
        f16x8 b1 = *(const f16x8*)(b1p + k0);
        acc[0][0] = __builtin_amdgcn_mfma_f32_16x16x32_f16(a0, b0, acc[0][0], 0, 0, 0);
        acc[0][1] = __builtin_amdgcn_mfma_f32_16x16x32_f16(a0, b1, acc[0][1], 0, 0, 0);
        acc[1][0] = __builtin_amdgcn_mfma_f32_16x16x32_f16(a1, b0, acc[1][0], 0, 0, 0);
        acc[1][1] = __builtin_amdgcn_mfma_f32_16x16x32_f16(a1, b1, acc[1][1], 0, 0, 0);
    }

    #pragma unroll
    for (int fi = 0; fi < 2; fi++)
        #pragma unroll
        for (int fj = 0; fj < 2; fj++) {
            int col = n0 + fj * 16 + rl;
            float bv = bias[col];
            #pragma unroll
            for (int r = 0; r < 4; r++) {
                int row = m0 + fi * 16 + kg * 4 + r;
                float v = acc[fi][fj][r] + bv;
                if (relu) v = fmaxf(v, 0.f);
                out[row * N + col] = (f16)v;
            }
        }
}

// ---------------- main fused kernel ----------------
// grid: (4 j-tiles, 18 c-pairs, 32 b), block 256 (4 waves)
// wave w: wr = w>>1 selects c within pair, wc = w&1 selects 64-col half of the 128-col j-tile
// A[m,k] = men[b,m,k] * vis[b,c,k] built in-register; acc += A @ aw1; epilogue reduces vs aw2.
__global__ __launch_bounds__(256) void attn_main(const f16* __restrict__ men,
                                                 const f16* __restrict__ vis,
                                                 const f16* __restrict__ aw1t,
                                                 const float* __restrict__ ab1,
                                                 const float* __restrict__ aw2,
                                                 float* __restrict__ out_acc) {
    int lane = threadIdx.x & 63;
    int w = threadIdx.x >> 6;
    int wr = w >> 1, wc = w & 1;
    int b = blockIdx.z, cp = blockIdx.y, jt = blockIdx.x;
    int c = cp * 2 + wr;
    int j0 = jt * 128 + wc * 64;
    int rl = lane & 15, kg = lane >> 4;

    const f16* menb = men + (b * NM + rl) * 512 + kg * 8;
    const f16* visb = vis + (b * NC + c) * 512 + kg * 8;
    const f16* awb  = aw1t + (j0 + rl) * 512 + kg * 8;

    f32x4 acc[4][4] = {};

    for (int k0 = 0; k0 < 512; k0 += 32) {
        f16x8 vv = *(const f16x8*)(visb + k0);
        f16x8 af[4], bf[4];
        #pragma unroll
        for (int fi = 0; fi < 4; fi++) {
            f16x8 mm = *(const f16x8*)(menb + fi * 16 * 512 + k0);
            af[fi] = mm * vv;   // packed f16 multiply
        }
        #pragma unroll
        for (int fj = 0; fj < 4; fj++)
            bf[fj] = *(const f16x8*)(awb + fj * 16 * 512 + k0);
        #pragma unroll
        for (int fi = 0; fi < 4; fi++)
            #pragma unroll
            for (int fj = 0; fj < 4; fj++)
                acc[fi][fj] = __builtin_amdgcn_mfma_f32_16x16x32_f16(af[fi], bf[fj], acc[fi][fj], 0, 0, 0);
    }

    // epilogue: partial[m] = sum over this wave's 64 j of relu(acc + ab1[j]) * aw2[j]  (fp32)
    float ab1v[4], aw2v[4];
    #pragma unroll
    for (int fj = 0; fj < 4; fj++) {
        int j = j0 + fj * 16 + rl;
        ab1v[fj] = ab1[j];
        aw2v[fj] = aw2[j];
    }
    float part[4][4];
    #pragma unroll
    for (int fi = 0; fi < 4; fi++)
        #pragma unroll
        for (int r = 0; r < 4; r++) {
            float s = 0.f;
            #pragma unroll
            for (int fj = 0; fj < 4; fj++) {
                float v = acc[fi][fj][r] + ab1v[fj];
                v = fmaxf(v, 0.f);
                s += v * aw2v[fj];
            }
            part[fi][r] = s;
        }
    // reduce across the 16 columns held by lanes differing in low 4 bits
    #pragma unroll
    for (int mask = 1; mask < 16; mask <<= 1)
        #pragma unroll
        for (int fi = 0; fi < 4; fi++)
            #pragma unroll
            for (int r = 0; r < 4; r++)
                part[fi][r] += __shfl_xor(part[fi][r], mask);

    // lane (rl, kg) owns (fi = rl>>2, r = rl&3) -> m = fi*16 + kg*4 + r  (all 64 m distinct)
    float myv = 0.f;
    #pragma unroll
    for (int fi = 0; fi < 4; fi++)
        #pragma unroll
        for (int r = 0; r < 4; r++)
            myv = (rl == fi * 4 + r) ? part[fi][r] : myv;
    int m = (rl >> 2) * 16 + kg * 4 + (rl & 3);
    atomicAdd(&out_acc[(b * NM + m) * NC + c], myv);
}

// ---------------- post-process: + ab2, masks, NEG_INF ----------------
__global__ __launch_bounds__(256) void postproc(float* __restrict__ out,
                                                const float* __restrict__ mm,
                                                const float* __restrict__ cm,
                                                const float* __restrict__ ab2) {
    int i = blockIdx.x * 256 + threadIdx.x;  // < 73728
    int b = i / (NM * NC);
    int rest = i - b * (NM * NC);
    int m = rest / NC, c = rest - m * NC;
    float t = (out[i] + ab2[0]) * mm[b * NM + m] * cm[b * NC + c];
    out[i] = (t != 0.f) ? t : NEG_INF_F;
}

extern "C" void kernel_launch(void* const* d_in, const int* in_sizes, int n_in,
                              void* d_out, int out_size, void* d_ws, size_t ws_size,
                              hipStream_t stream) {
    const float* ME  = (const float*)d_in[0];   // (32,64,1024)
    const float* CL  = (const float*)d_in[1];   // (32,36,1000)
    const float* MM  = (const float*)d_in[2];   // (32,64)
    const float* CM  = (const float*)d_in[3];   // (32,36)
    const float* VW1 = (const float*)d_in[4];   // (1000,512)
    const float* VB1 = (const float*)d_in[5];
    const float* VW2 = (const float*)d_in[6];   // (512,512)
    const float* VB2 = (const float*)d_in[7];
    const float* MW1 = (const float*)d_in[8];   // (1024,512)
    const float* MB1 = (const float*)d_in[9];
    const float* MW2 = (const float*)d_in[10];  // (512,512)
    const float* MB2 = (const float*)d_in[11];
    const float* AW1 = (const float*)d_in[12];  // (512,512)
    const float* AB1 = (const float*)d_in[13];
    const float* AW2 = (const float*)d_in[14];  // (512,1)
    const float* AB2 = (const float*)d_in[15];  // (1,)
    float* out = (float*)d_out;

    char* ws = (char*)d_ws;
    f16* me_h  = (f16*)ws; ws += (size_t)2048 * 1024 * 2;
    f16* cl_h  = (f16*)ws; ws += (size_t)1152 * 1024 * 2;
    f16* mw1t  = (f16*)ws; ws += (size_t)512 * 1024 * 2;
    f16* mw2t  = (f16*)ws; ws += (size_t)512 * 512 * 2;
    f16* vw1t  = (f16*)ws; ws += (size_t)512 * 1024 * 2;
    f16* vw2t  = (f16*)ws; ws += (size_t)512 * 512 * 2;
    f16* aw1t  = (f16*)ws; ws += (size_t)512 * 512 * 2;
    f16* men1  = (f16*)ws; ws += (size_t)2048 * 512 * 2;
    f16* menh  = (f16*)ws; ws += (size_t)2048 * 512 * 2;
    f16* vis1  = (f16*)ws; ws += (size_t)1152 * 512 * 2;
    f16* vish  = (f16*)ws; ws += (size_t)1152 * 512 * 2;

    hipMemsetAsync(d_out, 0, (size_t)73728 * sizeof(float), stream);

    cvt_dense<<<2048 * 1024 / 256, 256, 0, stream>>>(ME, me_h, 2048 * 1024);
    cvt_pad1024<<<1152 * 1024 / 256, 256, 0, stream>>>(CL, cl_h, 1152, 1000);
    cvt_transpose<<<512 * 1024 / 256, 256, 0, stream>>>(MW1, mw1t, 1024, 1024);
    cvt_transpose<<<512 * 512 / 256, 256, 0, stream>>>(MW2, mw2t, 512, 512);
    cvt_transpose<<<512 * 1024 / 256, 256, 0, stream>>>(VW1, vw1t, 1000, 1024);
    cvt_transpose<<<512 * 512 / 256, 256, 0, stream>>>(VW2, vw2t, 512, 512);
    cvt_transpose<<<512 * 512 / 256, 256, 0, stream>>>(AW1, aw1t, 512, 512);

    // men1 = relu(ME @ mw1 + mb1); men = men1 @ mw2 + mb2
    gemm16<<<dim3(2048 / 64, 512 / 64), 256, 0, stream>>>(me_h, mw1t, MB1, men1, 1024, 512, 1);
    gemm16<<<dim3(2048 / 64, 512 / 64), 256, 0, stream>>>(men1, mw2t, MB2, menh, 512, 512, 0);
    // vis1 = relu(CL @ vw1 + vb1); vis = vis1 @ vw2 + vb2
    gemm16<<<dim3(1152 / 64, 512 / 64), 256, 0, stream>>>(cl_h, vw1t, VB1, vis1, 1024, 512, 1);
    gemm16<<<dim3(1152 / 64, 512 / 64), 256, 0, stream>>>(vis1, vw2t, VB2, vish, 512, 512, 0);

    attn_main<<<dim3(4, 18, 32), 256, 0, stream>>>(menh, vish, aw1t, AB1, AW2, out);

    postproc<<<73728 / 256, 256, 0, stream>>>(out, MM, CM, AB2);
}

// Round 5
// 212.890 us; speedup vs baseline: 1.0708x; 1.0708x over previous
//
#include <hip/hip_runtime.h>
#include <hip/hip_bf16.h>

typedef _Float16 f16;
typedef _Float16 f16x8 __attribute__((ext_vector_type(8)));
typedef float f32x4 __attribute__((ext_vector_type(4)));

#define NB 32
#define NM 64
#define NC 36
#define NEG_INF_F (-1e10f)

// ---------------- conversion kernels ----------------

__global__ __launch_bounds__(256) void cvt_dense(const float* __restrict__ in,
                                                 f16* __restrict__ out, int n) {
    int i = blockIdx.x * 256 + threadIdx.x;
    if (i < n) out[i] = (f16)in[i];
}

// out: rows x 1024 (zero-padded), in: rows x K
__global__ __launch_bounds__(256) void cvt_pad1024(const float* __restrict__ in,
                                                   f16* __restrict__ out, int rows, int K) {
    int i = blockIdx.x * 256 + threadIdx.x;
    int r = i >> 10, k = i & 1023;
    if (r < rows) out[i] = (k < K) ? (f16)in[r * K + k] : (f16)0.f;
}

// w: K x 512 (row-major f32) -> wt: 512 x Kp (f16, k-major, zero-padded)
__global__ __launch_bounds__(256) void cvt_transpose(const float* __restrict__ w,
                                                     f16* __restrict__ wt, int K, int Kp) {
    int i = blockIdx.x * 256 + threadIdx.x;
    int n = i & 511;
    int k = i >> 9;
    if (k < Kp) wt[n * Kp + k] = (k < K) ? (f16)w[k * 512 + n] : (f16)0.f;
}

// ---------------- generic f16 MFMA GEMM: out = act(A @ Wt^T + bias) ----------------
__global__ __launch_bounds__(256) void gemm16(const f16* __restrict__ A,
                                              const f16* __restrict__ Wt,
                                              const float* __restrict__ bias,
                                              f16* __restrict__ out,
                                              int K, int N, int relu) {
    int lane = threadIdx.x & 63;
    int w = threadIdx.x >> 6;
    int wr = w >> 1, wc = w & 1;
    int m0 = blockIdx.x * 64 + wr * 32;
    int n0 = blockIdx.y * 64 + wc * 32;
    int rl = lane & 15, kg = lane >> 4;

    f32x4 acc[2][2] = {};

    const f16* a0p = A + (m0 + rl) * K + kg * 8;
    const f16* a1p = a0p + 16 * K;
    const f16* b0p = Wt + (n0 + rl) * K + kg * 8;
    const f16* b1p = b0p + 16 * K;

    for (int k0 = 0; k0 < K; k0 += 32) {
        f16x8 a0 = *(const f16x8*)(a0p + k0);
        f16x8 a1 = *(const f16x8*)(a1p + k0);
        f16x8 b0 = *(const f16x8*)(b0p + k0);
        f16x8 b1 = *(const f16x8*)(b1p + k0);
        acc[0][0] = __builtin_amdgcn_mfma_f32_16x16x32_f16(a0, b0, acc[0][0], 0, 0, 0);
        acc[0][1] = __builtin_amdgcn_mfma_f32_16x16x32_f16(a0, b1, acc[0][1], 0, 0, 0);
        acc[1][0] = __builtin_amdgcn_mfma_f32_16x16x32_f16(a1, b0, acc[1][0], 0, 0, 0);
        acc[1][1] = __builtin_amdgcn_mfma_f32_16x16x32_f16(a1, b1, acc[1][1], 0, 0, 0);
    }

    #pragma unroll
    for (int fi = 0; fi < 2; fi++)
        #pragma unroll
        for (int fj = 0; fj < 2; fj++) {
            int col = n0 + fj * 16 + rl;
            float bv = bias[col];
            #pragma unroll
            for (int r = 0; r < 4; r++) {
                int row = m0 + fi * 16 + kg * 4 + r;
                float v = acc[fi][fj][r] + bv;
                if (relu) v = fmaxf(v, 0.f);
                out[row * N + col] = (f16)v;
            }
        }
}

// ---------------- main fused kernel ----------------
// grid: (2 jt, 18 cp, 32 b), block 256 (4 waves).
// Wave w handles j0 = jt*256 + w*64 and BOTH c's of the pair: men & aw1 fragments
// are amortized over 2 c values -> 10 loads per 32 MFMAs per K-step.
__global__ __launch_bounds__(256, 2) void attn_main(const f16* __restrict__ men,
                                                    const f16* __restrict__ vis,
                                                    const f16* __restrict__ aw1t,
                                                    const float* __restrict__ ab1,
                                                    const float* __restrict__ aw2,
                                                    float* __restrict__ out_acc) {
    int lane = threadIdx.x & 63;
    int w = threadIdx.x >> 6;
    int b = blockIdx.z, cp = blockIdx.y, jt = blockIdx.x;
    int c0 = cp * 2;
    int j0 = jt * 256 + w * 64;
    int rl = lane & 15, kg = lane >> 4;

    const f16* menb  = men + (b * NM + rl) * 512 + kg * 8;
    const f16* visb0 = vis + (b * NC + c0) * 512 + kg * 8;
    const f16* awb   = aw1t + (j0 + rl) * 512 + kg * 8;

    f32x4 acc0[4][4] = {};
    f32x4 acc1[4][4] = {};

    for (int k0 = 0; k0 < 512; k0 += 32) {
        f16x8 vv0 = *(const f16x8*)(visb0 + k0);
        f16x8 vv1 = *(const f16x8*)(visb0 + 512 + k0);
        f16x8 mm[4], bf[4];
        #pragma unroll
        for (int fi = 0; fi < 4; fi++)
            mm[fi] = *(const f16x8*)(menb + fi * 16 * 512 + k0);
        #pragma unroll
        for (int fj = 0; fj < 4; fj++)
            bf[fj] = *(const f16x8*)(awb + fj * 16 * 512 + k0);

        #pragma unroll
        for (int fi = 0; fi < 4; fi++) {
            f16x8 a0 = mm[fi] * vv0;   // packed f16 multiply
            #pragma unroll
            for (int fj = 0; fj < 4; fj++)
                acc0[fi][fj] = __builtin_amdgcn_mfma_f32_16x16x32_f16(a0, bf[fj], acc0[fi][fj], 0, 0, 0);
        }
        #pragma unroll
        for (int fi = 0; fi < 4; fi++) {
            f16x8 a1 = mm[fi] * vv1;
            #pragma unroll
            for (int fj = 0; fj < 4; fj++)
                acc1[fi][fj] = __builtin_amdgcn_mfma_f32_16x16x32_f16(a1, bf[fj], acc1[fi][fj], 0, 0, 0);
        }
    }

    // epilogue (fp32): part[m] = sum_j relu(acc + ab1[j]) * aw2[j], for both c
    float ab1v[4], aw2v[4];
    #pragma unroll
    for (int fj = 0; fj < 4; fj++) {
        int j = j0 + fj * 16 + rl;
        ab1v[fj] = ab1[j];
        aw2v[fj] = aw2[j];
    }
    float part0[4][4], part1[4][4];
    #pragma unroll
    for (int fi = 0; fi < 4; fi++)
        #pragma unroll
        for (int r = 0; r < 4; r++) {
            float s0 = 0.f, s1 = 0.f;
            #pragma unroll
            for (int fj = 0; fj < 4; fj++) {
                float v0 = fmaxf(acc0[fi][fj][r] + ab1v[fj], 0.f);
                float v1 = fmaxf(acc1[fi][fj][r] + ab1v[fj], 0.f);
                s0 += v0 * aw2v[fj];
                s1 += v1 * aw2v[fj];
            }
            part0[fi][r] = s0;
            part1[fi][r] = s1;
        }
    #pragma unroll
    for (int mask = 1; mask < 16; mask <<= 1)
        #pragma unroll
        for (int fi = 0; fi < 4; fi++)
            #pragma unroll
            for (int r = 0; r < 4; r++) {
                part0[fi][r] += __shfl_xor(part0[fi][r], mask);
                part1[fi][r] += __shfl_xor(part1[fi][r], mask);
            }

    // lane (rl, kg) owns (fi = rl>>2, r = rl&3) -> m = (rl>>2)*16 + kg*4 + (rl&3)
    float myv0 = 0.f, myv1 = 0.f;
    #pragma unroll
    for (int fi = 0; fi < 4; fi++)
        #pragma unroll
        for (int r = 0; r < 4; r++) {
            bool sel = (rl == fi * 4 + r);
            myv0 = sel ? part0[fi][r] : myv0;
            myv1 = sel ? part1[fi][r] : myv1;
        }
    int m = (rl >> 2) * 16 + kg * 4 + (rl & 3);
    atomicAdd(&out_acc[(b * NM + m) * NC + c0], myv0);
    atomicAdd(&out_acc[(b * NM + m) * NC + c0 + 1], myv1);
}

// ---------------- post-process: + ab2, masks, NEG_INF ----------------
__global__ __launch_bounds__(256) void postproc(float* __restrict__ out,
                                                const float* __restrict__ mm,
                                                const float* __restrict__ cm,
                                                const float* __restrict__ ab2) {
    int i = blockIdx.x * 256 + threadIdx.x;  // < 73728
    int b = i / (NM * NC);
    int rest = i - b * (NM * NC);
    int m = rest / NC, c = rest - m * NC;
    float t = (out[i] + ab2[0]) * mm[b * NM + m] * cm[b * NC + c];
    out[i] = (t != 0.f) ? t : NEG_INF_F;
}

extern "C" void kernel_launch(void* const* d_in, const int* in_sizes, int n_in,
                              void* d_out, int out_size, void* d_ws, size_t ws_size,
                              hipStream_t stream) {
    const float* ME  = (const float*)d_in[0];   // (32,64,1024)
    const float* CL  = (const float*)d_in[1];   // (32,36,1000)
    const float* MM  = (const float*)d_in[2];   // (32,64)
    const float* CM  = (const float*)d_in[3];   // (32,36)
    const float* VW1 = (const float*)d_in[4];   // (1000,512)
    const float* VB1 = (const float*)d_in[5];
    const float* VW2 = (const float*)d_in[6];   // (512,512)
    const float* VB2 = (const float*)d_in[7];
    const float* MW1 = (const float*)d_in[8];   // (1024,512)
    const float* MB1 = (const float*)d_in[9];
    const float* MW2 = (const float*)d_in[10];  // (512,512)
    const float* MB2 = (const float*)d_in[11];
    const float* AW1 = (const float*)d_in[12];  // (512,512)
    const float* AB1 = (const float*)d_in[13];
    const float* AW2 = (const float*)d_in[14];  // (512,1)
    const float* AB2 = (const float*)d_in[15];  // (1,)
    float* out = (float*)d_out;

    char* ws = (char*)d_ws;
    f16* me_h  = (f16*)ws; ws += (size_t)2048 * 1024 * 2;
    f16* cl_h  = (f16*)ws; ws += (size_t)1152 * 1024 * 2;
    f16* mw1t  = (f16*)ws; ws += (size_t)512 * 1024 * 2;
    f16* mw2t  = (f16*)ws; ws += (size_t)512 * 512 * 2;
    f16* vw1t  = (f16*)ws; ws += (size_t)512 * 1024 * 2;
    f16* vw2t  = (f16*)ws; ws += (size_t)512 * 512 * 2;
    f16* aw1t  = (f16*)ws; ws += (size_t)512 * 512 * 2;
    f16* men1  = (f16*)ws; ws += (size_t)2048 * 512 * 2;
    f16* menh  = (f16*)ws; ws += (size_t)2048 * 512 * 2;
    f16* vis1  = (f16*)ws; ws += (size_t)1152 * 512 * 2;
    f16* vish  = (f16*)ws; ws += (size_t)1152 * 512 * 2;

    hipMemsetAsync(d_out, 0, (size_t)73728 * sizeof(float), stream);

    cvt_dense<<<2048 * 1024 / 256, 256, 0, stream>>>(ME, me_h, 2048 * 1024);
    cvt_pad1024<<<1152 * 1024 / 256, 256, 0, stream>>>(CL, cl_h, 1152, 1000);
    cvt_transpose<<<512 * 1024 / 256, 256, 0, stream>>>(MW1, mw1t, 1024, 1024);
    cvt_transpose<<<512 * 512 / 256, 256, 0, stream>>>(MW2, mw2t, 512, 512);
    cvt_transpose<<<512 * 1024 / 256, 256, 0, stream>>>(VW1, vw1t, 1000, 1024);
    cvt_transpose<<<512 * 512 / 256, 256, 0, stream>>>(VW2, vw2t, 512, 512);
    cvt_transpose<<<512 * 512 / 256, 256, 0, stream>>>(AW1, aw1t, 512, 512);

    gemm16<<<dim3(2048 / 64, 512 / 64), 256, 0, stream>>>(me_h, mw1t, MB1, men1, 1024, 512, 1);
    gemm16<<<dim3(2048 / 64, 512 / 64), 256, 0, stream>>>(men1, mw2t, MB2, menh, 512, 512, 0);
    gemm16<<<dim3(1152 / 64, 512 / 64), 256, 0, stream>>>(cl_h, vw1t, VB1, vis1, 1024, 512, 1);
    gemm16<<<dim3(1152 / 64, 512 / 64), 256, 0, stream>>>(vis1, vw2t, VB2, vish, 512, 512, 0);

    attn_main<<<dim3(2, 18, 32), 256, 0, stream>>>(menh, vish, aw1t, AB1, AW2, out);

    postproc<<<73728 / 256, 256, 0, stream>>>(out, MM, CM, AB2);
}